// Round 9
// baseline (221.651 us; speedup 1.0000x reference)
//
#include <hip/hip_runtime.h>
#include <hip/hip_bf16.h>
#include <math.h>

#define B_ 8
#define L_ 1024
#define DM 256
#define DI 512
#define HD 32
#define NH 16
#define DS 128
#define CDIM 768
#define NZX 1280    // z + xBC cols (dt computed separately)
#define CH 256
#define NC 4
#define M_ (B_*L_)
#define EPSV 1e-5f

typedef short bf16x8 __attribute__((ext_vector_type(8)));
typedef float f32x4 __attribute__((ext_vector_type(4)));

// ---- workspace layout (float units) ----
#define OFF_ZX   0                         // M_*NZX bf16
#define SZ_ZX    (M_*NZX/2)
#define OFF_XC   (OFF_ZX+SZ_ZX)            // M_*CDIM bf16
#define SZ_XC    (M_*CDIM/2)
#define OFF_DT   (OFF_XC+SZ_XC)            // M_*NH fp32
#define SZ_DT    (M_*NH)
#define OFF_S0   (OFF_DT+SZ_DT)            // bf16 S0b
#define SZ_S0    (B_*NC*CH*CH/2)
#define OFF_Y    (OFF_S0+SZ_S0)            // M_*DI bf16
#define SZ_Y     (M_*DI/2)
#define OFF_YNB  (OFF_Y+SZ_Y)              // M_*DI bf16
#define SZ_YNB   (M_*DI/2)
#define OFF_XBF  (OFF_YNB+SZ_YNB)          // M_*DM bf16
#define SZ_XBF   (M_*DM/2)
#define OFF_WBF  (OFF_XBF+SZ_XBF)          // 1296*DM bf16
#define SZ_WBF   (1296*DM/2)
#define OFF_WOBF (OFF_WBF+SZ_WBF)          // DM*DI bf16
#define SZ_WOBF  (DM*DI/2)
#define OFF_GNP  (OFF_WOBF+SZ_WOBF)        // 64 float2 group accumulators
#define SZ_GNP   (64*2)
#define OFF_BT   (OFF_GNP+SZ_GNP)          // B^T: 32*128*256 bf16
#define SZ_BT    (32*128*256/2)
#define OFF_OUTB (OFF_BT+SZ_BT)            // pre-GN out bf16: M_*DM
#define SZ_OUTB  (M_*DM/2)

__device__ __forceinline__ ushort f2bf(float v) {
  __hip_bfloat16 h = __float2bfloat16(v);
  return *(ushort*)&h;
}
__device__ __forceinline__ float bf2f(ushort u) {
  return __uint_as_float(((unsigned int)u) << 16);
}

// ---------- fused prep: x transpose+cast, W casts, gnp zero, dt (exact fp32) ----------
__global__ __launch_bounds__(256) void k_prep(const float* __restrict__ x,
                                              const float* __restrict__ W_in,
                                              const float* __restrict__ W_out,
                                              const float* __restrict__ dt_bias,
                                              ushort* __restrict__ xbf,
                                              ushort* __restrict__ wbf,
                                              ushort* __restrict__ wobf,
                                              float2* __restrict__ gnp,
                                              float* __restrict__ dtb) {
  __shared__ float Ts[64][65];
  __shared__ float Xs[256][16];
  __shared__ float Ws[16][257];
  const int bid = blockIdx.x;
  const int t = threadIdx.x;
  if (bid < 512) {
    const int kt = bid & 3, lt = (bid >> 2) & 15, b = bid >> 6;
    const int k0 = kt*64, l0 = lt*64;
    for (int i = t; i < 4096; i += 256) {
      int kk = i>>6, ll = i&63;
      Ts[kk][ll] = x[(size_t)b*DM*L_ + (size_t)(k0+kk)*L_ + l0+ll];
    }
    __syncthreads();
    for (int i = t; i < 4096; i += 256) {
      int mm = i>>6, kk = i&63;
      xbf[(size_t)(b*L_ + l0+mm)*DM + k0+kk] = f2bf(Ts[kk][mm]);
    }
  } else if (bid < 512 + 1296) {
    int i = (bid-512)*256 + t;
    if (i < 1296*DM) wbf[i] = f2bf(W_in[i]);
  } else if (bid < 512 + 1296 + 512) {
    int i = (bid-512-1296)*256 + t;
    wobf[i] = f2bf(W_out[i]);
  } else if (bid == 2320) {
    if (t < 64) gnp[t] = make_float2(0.f, 0.f);
  } else {
    const int bm = (bid - 2321)*16;
    const int b = bm >> 10, l0 = bm & 1023;
    for (int i = t; i < 4096; i += 256) {
      int h = i>>8, k = i&255;
      Ws[h][k] = W_in[(size_t)(NZX+h)*DM + k];
    }
    for (int i = t; i < 4096; i += 256) {
      int k = i>>4, li = i&15;
      Xs[k][li] = x[(size_t)b*DM*L_ + (size_t)k*L_ + l0+li];
    }
    __syncthreads();
    const int h = t&15, li = t>>4;
    float acc = 0.f;
#pragma unroll 8
    for (int k = 0; k < 256; ++k) acc += Xs[k][li]*Ws[h][k];
    float v = acc + dt_bias[h];
    dtb[(size_t)bm*NH + t] = (v > 20.f) ? v : log1pf(expf(v));
  }
}

// ---------- in-proj GEMM (bf16 MFMA, 128x128 tile, double-buffered) ----------
__global__ __launch_bounds__(256) void k_gemm_in_mfma(const ushort* __restrict__ xbf,
                                                      const ushort* __restrict__ wbf,
                                                      ushort* __restrict__ zxb) {
  __shared__ ushort As[2][128*40];
  __shared__ ushort Bs[2][128*40];
  const int tid = threadIdx.x;
  const int n0 = blockIdx.x*128, m0 = blockIdx.y*128;
  const int wave = tid>>6, lane = tid&63;
  const int lr = lane&15, quad = lane>>4;
  f32x4 acc[2][8];
#pragma unroll
  for (int mi=0;mi<2;++mi)
#pragma unroll
    for (int ni=0;ni<8;++ni)
#pragma unroll
      for (int r=0;r<4;++r) acc[mi][ni][r] = 0.f;
  const int srow = tid>>1, sc = (tid&1)*16;
  auto LOAD = [&](int buf, int k0) {
    *(uint4*)&As[buf][srow*40 + sc]     = *(const uint4*)(xbf + (size_t)(m0+srow)*DM + k0 + sc);
    *(uint4*)&As[buf][srow*40 + sc + 8] = *(const uint4*)(xbf + (size_t)(m0+srow)*DM + k0 + sc + 8);
    *(uint4*)&Bs[buf][srow*40 + sc]     = *(const uint4*)(wbf + (size_t)(n0+srow)*DM + k0 + sc);
    *(uint4*)&Bs[buf][srow*40 + sc + 8] = *(const uint4*)(wbf + (size_t)(n0+srow)*DM + k0 + sc + 8);
  };
  LOAD(0, 0);
#pragma unroll
  for (int i = 0; i < 8; ++i) {
    __syncthreads();
    if (i < 7) LOAD((i+1)&1, (i+1)*32);
    const int cur = i&1;
    bf16x8 af[2], bfr[8];
    af[0] = *(const bf16x8*)&As[cur][(wave*32+lr)*40 + quad*8];
    af[1] = *(const bf16x8*)&As[cur][(wave*32+16+lr)*40 + quad*8];
#pragma unroll
    for (int ni=0;ni<8;++ni) bfr[ni] = *(const bf16x8*)&Bs[cur][(ni*16+lr)*40 + quad*8];
#pragma unroll
    for (int mi=0;mi<2;++mi)
#pragma unroll
      for (int ni=0;ni<8;++ni)
        acc[mi][ni] = __builtin_amdgcn_mfma_f32_16x16x32_bf16(af[mi], bfr[ni], acc[mi][ni], 0, 0, 0);
  }
#pragma unroll
  for (int mi=0;mi<2;++mi) {
    int m = m0 + wave*32 + mi*16 + quad*4;
#pragma unroll
    for (int ni=0;ni<8;++ni) {
      int n = n0 + ni*16 + lr;
#pragma unroll
      for (int r=0;r<4;++r) zxb[(size_t)(m+r)*NZX + n] = f2bf(acc[mi][ni][r]);
    }
  }
}

// ---------- conv4 + SiLU -> bf16 xcb (+ direct B^T write) ----------
__global__ __launch_bounds__(256) void k_conv(const ushort* __restrict__ zxb,
                                              const float* __restrict__ cw,
                                              const float* __restrict__ cb,
                                              ushort* __restrict__ xcb,
                                              ushort* __restrict__ btg) {
  const int j = blockIdx.x*256 + threadIdx.x;          // 0..767
  const int m8 = blockIdx.y*8;
  const int l0 = m8 & 1023;
  const int mb = m8 & ~1023;
  const float4 w = *(const float4*)&cw[j*4];
  const float bias = cb[j];
  float v[11];
#pragma unroll
  for (int i = 0; i < 11; ++i) {
    int ll = l0 - 3 + i;
    v[i] = (ll >= 0) ? bf2f(zxb[(size_t)(mb+ll)*NZX + DI + j]) : 0.f;
  }
  union { ushort u[8]; uint4 q; } res;
#pragma unroll
  for (int i = 0; i < 8; ++i) {
    float a = bias + w.x*v[i] + w.y*v[i+1] + w.z*v[i+2] + w.w*v[i+3];
    a = a / (1.f + expf(-a));
    res.u[i] = f2bf(a);
    xcb[(size_t)(mb+l0+i)*CDIM + j] = res.u[i];
  }
  if (j >= DI && j < DI+DS) {
    const int n = j - DI;
    const int bc = (mb >> 10)*NC + (l0 >> 8);
    const int lc = l0 & 255;
    *(uint4*)&btg[((size_t)bc*DS + n)*CH + lc] = res.q;
  }
}

// ---------- S0b = Cm·Bm^T (bf16 MFMA, lower-triangular tiles only) ----------
__global__ __launch_bounds__(256) void k_s0_mfma(const ushort* __restrict__ xcb,
                                                 ushort* __restrict__ S0b) {
  const int lt = blockIdx.x, st = blockIdx.y, bc = blockIdx.z;
  if (st > lt) return;
  const int base = bc*CH;
  const int t = threadIdx.x;
  const int wave = t>>6, lane = t&63, lr = lane&15, quad = lane>>4;
  const int l = lt*64 + wave*16 + lr;
  f32x4 acc[4];
#pragma unroll
  for (int nt = 0; nt < 4; ++nt)
#pragma unroll
    for (int r = 0; r < 4; ++r) acc[nt][r] = 0.f;
#pragma unroll
  for (int ks = 0; ks < 4; ++ks) {
    bf16x8 af = *(const bf16x8*)(xcb + (size_t)(base+l)*CDIM + (DI+DS) + ks*32 + quad*8);
#pragma unroll
    for (int nt = 0; nt < 4; ++nt) {
      bf16x8 bf = *(const bf16x8*)(xcb + (size_t)(base + st*64 + nt*16 + lr)*CDIM + DI + ks*32 + quad*8);
      acc[nt] = __builtin_amdgcn_mfma_f32_16x16x32_bf16(af, bf, acc[nt], 0, 0, 0);
    }
  }
#pragma unroll
  for (int nt = 0; nt < 4; ++nt)
#pragma unroll
    for (int r = 0; r < 4; ++r)
      S0b[((size_t)bc*CH + lt*64 + wave*16 + quad*4 + r)*CH + st*64 + nt*16 + lr] = f2bf(acc[nt][r]);
}

// ---------- fused SSD: per (b,h,p-half), sequential over chunks ----------
// carries inter-chunk state P[16p][128n] in registers; Y = Y_diag + Y_off + D*xs
__global__ __launch_bounds__(256) void k_ssd(const ushort* __restrict__ xcb,
                                             const ushort* __restrict__ btg,
                                             const float* __restrict__ dtb,
                                             const float* __restrict__ A_log,
                                             const ushort* __restrict__ S0b,
                                             const float* __restrict__ Dp,
                                             ushort* __restrict__ Yb) {
  __shared__ float acs[CH];
  __shared__ float E8[CH];
  __shared__ ushort Xt[16][264];   // X^T (p-half), row stride 264 (2-way banks, 16B aligned)
  __shared__ ushort Xw[16][264];   // X^T * wv
  __shared__ ushort Pl[16][136];   // prev state bf16 [p][n]
  const int t = threadIdx.x;
  const int b = blockIdx.x, h = blockIdx.y, ph = blockIdx.z;
  const int wave = t>>6, lane = t&63, lr = lane&15, quad = lane>>4;
  const float An = -expf(A_log[h]);
  const float dph = Dp[h];
  // running P registers: [nt][r] -> P[p=quad*4+r][n=wave*32+nt*16+lr]
  f32x4 P[2];
#pragma unroll
  for (int nt=0;nt<2;++nt)
#pragma unroll
    for (int r=0;r<4;++r) P[nt][r] = 0.f;

  for (int c = 0; c < NC; ++c) {
    const int bc = b*NC + c;
    const int base = bc*CH;
    __syncthreads();                       // protect LDS reuse from previous chunk
    float dt_t = dtb[(size_t)(base+t)*NH + h];
    acs[t] = dt_t * An;
    __syncthreads();
    for (int off = 1; off < CH; off <<= 1) {
      float v = (t >= off) ? acs[t-off] : 0.f;
      __syncthreads();
      acs[t] += v;
      __syncthreads();
    }
    const float alast = acs[CH-1];
    const float wv_t = expf(alast - acs[t]) * dt_t;
    E8[t] = expf(acs[t & ~7] - acs[t]) * dt_t;
    {
      const ushort* xp = xcb + (size_t)(base+t)*CDIM + h*HD + ph*16;
      ushort tmp[16];
      *(uint4*)&tmp[0] = *(const uint4*)(xp);
      *(uint4*)&tmp[8] = *(const uint4*)(xp+8);
#pragma unroll
      for (int p = 0; p < 16; ++p) {
        Xt[p][t] = tmp[p];
        Xw[p][t] = f2bf(bf2f(tmp[p]) * wv_t);
      }
    }
    if (c > 0) {
#pragma unroll
      for (int nt = 0; nt < 2; ++nt)
#pragma unroll
        for (int r = 0; r < 4; ++r)
          Pl[quad*4+r][wave*32 + nt*16 + lr] = f2bf(P[nt][r]);
    }
    __syncthreads();

    f32x4 acc[4];
#pragma unroll
    for (int mt=0;mt<4;++mt)
#pragma unroll
      for (int r=0;r<4;++r) acc[mt][r] = 0.f;

    // ---- Y_off: C @ prev^T  (prev from Pl) ----
    if (c > 0) {
#pragma unroll
      for (int ks = 0; ks < 4; ++ks) {
        bf16x8 bf = *(const bf16x8*)&Pl[lr][ks*32 + quad*8];
#pragma unroll
        for (int mt = 0; mt < 4; ++mt) {
          int l = wave*64 + mt*16 + lr;
          bf16x8 af = *(const bf16x8*)(xcb + (size_t)(base+l)*CDIM + (DI+DS) + ks*32 + quad*8);
          acc[mt] = __builtin_amdgcn_mfma_f32_16x16x32_bf16(af, bf, acc[mt], 0,0,0);
        }
      }
#pragma unroll
      for (int mt = 0; mt < 4; ++mt)
#pragma unroll
        for (int r = 0; r < 4; ++r)
          acc[mt][r] *= expf(acs[wave*64 + mt*16 + quad*4 + r]);
    }

    // ---- states: st[p][n] = (X*wv)^T @ B  (skip for last chunk) ----
    f32x4 stacc[2];
#pragma unroll
    for (int nt=0;nt<2;++nt)
#pragma unroll
      for (int r=0;r<4;++r) stacc[nt][r] = 0.f;
    if (c < NC-1) {
      const ushort* bp = btg + (size_t)bc*DS*CH;
#pragma unroll
      for (int k0 = 0; k0 < CH; k0 += 32) {
        bf16x8 a0 = *(const bf16x8*)&Xw[lr][k0 + quad*8];
        bf16x8 b0 = *(const bf16x8*)(bp + (size_t)(wave*32 + lr)*CH + k0 + quad*8);
        bf16x8 b1 = *(const bf16x8*)(bp + (size_t)(wave*32 + 16 + lr)*CH + k0 + quad*8);
        stacc[0] = __builtin_amdgcn_mfma_f32_16x16x32_bf16(a0, b0, stacc[0], 0,0,0);
        stacc[1] = __builtin_amdgcn_mfma_f32_16x16x32_bf16(a0, b1, stacc[1], 0,0,0);
      }
    }

    // ---- Y_diag: masked M @ X^T ----
    float al[4];
#pragma unroll
    for (int mt = 0; mt < 4; ++mt) al[mt] = acs[wave*64 + mt*16 + lr];
    const int km3 = 2*wave + 1;
    for (int ks = 0; ks <= km3; ++ks) {
      const int sq = ks*32 + quad*8;
      const float as0 = acs[sq];
      const float4 e0 = *(const float4*)&E8[sq];
      const float4 e1 = *(const float4*)&E8[sq+4];
      const bf16x8 xb0 = *(const bf16x8*)&Xt[lr][sq];
      const float ev[8] = {e0.x,e0.y,e0.z,e0.w,e1.x,e1.y,e1.z,e1.w};
#pragma unroll
      for (int mt = 0; mt < 4; ++mt) {
        if (ks > ((wave*64 + mt*16 + 15) >> 5)) continue;
        const int l = wave*64 + mt*16 + lr;
        const bf16x8 sb = *(const bf16x8*)(S0b + ((size_t)bc*CH + l)*CH + sq);
        const float el = expf(al[mt] - as0);
        bf16x8 mf;
#pragma unroll
        for (int j = 0; j < 8; ++j) {
          float v = (sq + j <= l) ? bf2f((ushort)sb[j]) * el * ev[j] : 0.f;
          mf[j] = (short)f2bf(v);
        }
        acc[mt] = __builtin_amdgcn_mfma_f32_16x16x32_bf16(mf, xb0, acc[mt], 0,0,0);
      }
    }

    // ---- skip + store ----
#pragma unroll
    for (int mt = 0; mt < 4; ++mt) {
      const int lb = wave*64 + mt*16 + quad*4;
#pragma unroll
      for (int r = 0; r < 4; ++r) {
        float xv = bf2f(Xt[lr][lb+r]);
        Yb[(size_t)(base+lb+r)*DI + h*HD + ph*16 + lr] = f2bf(acc[mt][r] + dph*xv);
      }
    }

    // ---- update running state ----
    if (c < NC-1) {
      const float eT = expf(alast);
#pragma unroll
      for (int nt = 0; nt < 2; ++nt)
#pragma unroll
        for (int r = 0; r < 4; ++r)
          P[nt][r] = stacc[nt][r] + eT * P[nt][r];
    }
  }
}

// ---------- gate + RMSNorm, wave-per-row, no barriers ----------
__global__ __launch_bounds__(256) void k_rms(const ushort* __restrict__ zxb,
                                             const ushort* __restrict__ Yb,
                                             const float* __restrict__ rw,
                                             ushort* __restrict__ yn) {
  const int m = blockIdx.x*4 + (threadIdx.x>>6);
  const int lane = threadIdx.x & 63;
  const int c0 = lane*8;
  bf16x8 zv = *(const bf16x8*)(zxb + (size_t)m*NZX + c0);
  bf16x8 yv = *(const bf16x8*)(Yb  + (size_t)m*DI  + c0);
  float y[8];
  float ss = 0.f;
#pragma unroll
  for (int j = 0; j < 8; ++j) {
    float z = bf2f((ushort)zv[j]);
    y[j] = bf2f((ushort)yv[j]) * z / (1.f + expf(-z));
    ss += y[j]*y[j];
  }
#pragma unroll
  for (int off = 1; off < 64; off <<= 1) ss += __shfl_xor(ss, off);
  const float inv = rsqrtf(ss * (1.f/DI) + EPSV);
  float4 w0 = *(const float4*)&rw[c0];
  float4 w1 = *(const float4*)&rw[c0+4];
  const float wv[8] = {w0.x,w0.y,w0.z,w0.w,w1.x,w1.y,w1.z,w1.w};
  union { ushort u[8]; uint4 q; } pk;
#pragma unroll
  for (int j = 0; j < 8; ++j) pk.u[j] = f2bf(y[j] * inv * wv[j]);
  *(uint4*)(yn + (size_t)m*DI + c0) = pk.q;
}

// ---------- out-proj GEMM (bf16 MFMA, double-buffered) -> bf16 outb + GN partials ----------
__global__ __launch_bounds__(256) void k_gemm_out_mfma(const ushort* __restrict__ ynbf,
                                                       const ushort* __restrict__ wobf,
                                                       ushort* __restrict__ outb,
                                                       float2* __restrict__ gnp) {
  __shared__ ushort As[2][128*40];
  __shared__ ushort Bs[2][64*40];
  const int tid = threadIdx.x;
  const int n0 = blockIdx.x*64, m0 = blockIdx.y*128;
  const int wave = tid>>6, lane = tid&63;
  const int lr = lane&15, quad = lane>>4;
  f32x4 acc[2][4];
#pragma unroll
  for (int mi=0;mi<2;++mi)
#pragma unroll
    for (int ni=0;ni<4;++ni)
#pragma unroll
      for (int r=0;r<4;++r) acc[mi][ni][r] = 0.f;
  const int srow = tid>>1, sc = (tid&1)*16;
  const int brow = tid>>2, bcol = (tid&3)*8;
  auto LOAD = [&](int buf, int k0) {
    *(uint4*)&As[buf][srow*40 + sc]     = *(const uint4*)(ynbf + (size_t)(m0+srow)*DI + k0 + sc);
    *(uint4*)&As[buf][srow*40 + sc + 8] = *(const uint4*)(ynbf + (size_t)(m0+srow)*DI + k0 + sc + 8);
    *(uint4*)&Bs[buf][brow*40 + bcol]   = *(const uint4*)(wobf + (size_t)(n0+brow)*DI + k0 + bcol);
  };
  LOAD(0, 0);
#pragma unroll
  for (int i = 0; i < 16; ++i) {
    __syncthreads();
    if (i < 15) LOAD((i+1)&1, (i+1)*32);
    const int cur = i&1;
    bf16x8 af[2], bfr[4];
    af[0] = *(const bf16x8*)&As[cur][(wave*32+lr)*40 + quad*8];
    af[1] = *(const bf16x8*)&As[cur][(wave*32+16+lr)*40 + quad*8];
#pragma unroll
    for (int ni=0;ni<4;++ni) bfr[ni] = *(const bf16x8*)&Bs[cur][(ni*16+lr)*40 + quad*8];
#pragma unroll
    for (int mi=0;mi<2;++mi)
#pragma unroll
      for (int ni=0;ni<4;++ni)
        acc[mi][ni] = __builtin_amdgcn_mfma_f32_16x16x32_bf16(af[mi], bfr[ni], acc[mi][ni], 0, 0, 0);
  }
  const int b = m0 >> 10, l0 = m0 & 1023;
  float s0=0.f, ss0=0.f, s1=0.f, ss1=0.f;
#pragma unroll
  for (int mi=0;mi<2;++mi) {
    int lb = l0 + wave*32 + mi*16 + quad*4;
#pragma unroll
    for (int ni=0;ni<4;++ni) {
      int n = n0 + ni*16 + lr;
      union { ushort u[4]; uint2 q; } pk;
#pragma unroll
      for (int r=0;r<4;++r) pk.u[r] = f2bf(acc[mi][ni][r]);
      *(uint2*)&outb[(size_t)b*DM*L_ + (size_t)n*L_ + lb] = pk.q;
      float ps = acc[mi][ni][0]+acc[mi][ni][1]+acc[mi][ni][2]+acc[mi][ni][3];
      float pq = acc[mi][ni][0]*acc[mi][ni][0]+acc[mi][ni][1]*acc[mi][ni][1]
               + acc[mi][ni][2]*acc[mi][ni][2]+acc[mi][ni][3]*acc[mi][ni][3];
      if (ni < 2) { s0 += ps; ss0 += pq; } else { s1 += ps; ss1 += pq; }
    }
  }
#pragma unroll
  for (int off = 32; off > 0; off >>= 1) {
    s0 += __shfl_down(s0, off); ss0 += __shfl_down(ss0, off);
    s1 += __shfl_down(s1, off); ss1 += __shfl_down(ss1, off);
  }
  __shared__ float red[4][4];
  if (lane == 0) { red[wave][0]=s0; red[wave][1]=ss0; red[wave][2]=s1; red[wave][3]=ss1; }
  __syncthreads();
  if (tid == 0) {
    float S0=0,Q0=0,S1=0,Q1=0;
#pragma unroll
    for (int wv2 = 0; wv2 < 4; ++wv2) { S0+=red[wv2][0]; Q0+=red[wv2][1]; S1+=red[wv2][2]; Q1+=red[wv2][3]; }
    int g0 = b*8 + (n0>>5);
    atomicAdd(&gnp[g0].x, S0);   atomicAdd(&gnp[g0].y, Q0);
    atomicAdd(&gnp[g0+1].x, S1); atomicAdd(&gnp[g0+1].y, Q1);
  }
}

// ---------- GroupNorm apply + Mish: bf16 in, fp32 out ----------
__global__ __launch_bounds__(256) void k_gn_apply(const float2* __restrict__ gnp,
                                                  const float* __restrict__ gw,
                                                  const float* __restrict__ gb,
                                                  const ushort* __restrict__ ob,
                                                  float* __restrict__ o) {
  const int ch = blockIdx.x & 255, b = blockIdx.x >> 8;
  const int t = threadIdx.x;
  float2 p = gnp[b*8 + (ch>>5)];
  const float mean = p.x * (1.f/(32.f*L_));
  const float var  = p.y * (1.f/(32.f*L_)) - mean*mean;
  const float inv  = rsqrtf(var + EPSV);
  const float w = gw[ch], bb = gb[ch];
  size_t base = (size_t)blockIdx.x * L_;
  ushort4 v = *(const ushort4*)&ob[base + t*4];
  float r[4] = {bf2f(v.x), bf2f(v.y), bf2f(v.z), bf2f(v.w)};
#pragma unroll
  for (int j = 0; j < 4; ++j) {
    float u = (r[j] - mean) * inv * w + bb;
    float m;
    if (u > 15.f) m = u;
    else {
      float e = expf(u);
      float a = 1.f + e;
      float a2 = a*a;
      m = u * (a2 - 1.f) / (a2 + 1.f);
    }
    r[j] = m;
  }
  *(float4*)&o[base + t*4] = make_float4(r[0], r[1], r[2], r[3]);
}

extern "C" void kernel_launch(void* const* d_in, const int* in_sizes, int n_in,
                              void* d_out, int out_size, void* d_ws, size_t ws_size,
                              hipStream_t stream) {
  const float* x       = (const float*)d_in[0];
  const float* W_in    = (const float*)d_in[1];
  const float* conv_w  = (const float*)d_in[2];
  const float* conv_b  = (const float*)d_in[3];
  const float* dt_bias = (const float*)d_in[4];
  const float* A_log   = (const float*)d_in[5];
  const float* Dp      = (const float*)d_in[6];
  const float* rms_w   = (const float*)d_in[7];
  const float* W_out   = (const float*)d_in[8];
  const float* gn_w    = (const float*)d_in[9];
  const float* gn_b    = (const float*)d_in[10];
  float* out = (float*)d_out;
  float* ws  = (float*)d_ws;

  ushort* zxb   = (ushort*)(ws + OFF_ZX);
  ushort* xcb   = (ushort*)(ws + OFF_XC);
  float*  dtb   = ws + OFF_DT;
  ushort* S0b   = (ushort*)(ws + OFF_S0);
  ushort* Ybb   = (ushort*)(ws + OFF_Y);
  ushort* ynbf  = (ushort*)(ws + OFF_YNB);
  ushort* xbf   = (ushort*)(ws + OFF_XBF);
  ushort* wbf   = (ushort*)(ws + OFF_WBF);
  ushort* wobf  = (ushort*)(ws + OFF_WOBF);
  float2* gnp   = (float2*)(ws + OFF_GNP);
  ushort* btg   = (ushort*)(ws + OFF_BT);
  ushort* outb  = (ushort*)(ws + OFF_OUTB);

  k_prep         <<<dim3(512+1296+512+1+512), 256, 0, stream>>>(x, W_in, W_out, dt_bias,
                                                                xbf, wbf, wobf, gnp, dtb);
  k_gemm_in_mfma <<<dim3(NZX/128, M_/128), 256, 0, stream>>>(xbf, wbf, zxb);
  k_conv         <<<dim3(3, M_/8), 256, 0, stream>>>(zxb, conv_w, conv_b, xcb, btg);
  k_s0_mfma      <<<dim3(4, 4, B_*NC), 256, 0, stream>>>(xcb, S0b);
  k_ssd          <<<dim3(B_, NH, 2), 256, 0, stream>>>(xcb, btg, dtb, A_log, S0b, Dp, Ybb);
  k_rms          <<<dim3(M_/4), 256, 0, stream>>>(zxb, Ybb, rms_w, ynbf);
  k_gemm_out_mfma<<<dim3(DM/64, M_/128), 256, 0, stream>>>(ynbf, wobf, outb, gnp);
  k_gn_apply     <<<dim3(B_*DM), 256, 0, stream>>>(gnp, gn_w, gn_b, outb, out);
}

// Round 10
// 190.558 us; speedup vs baseline: 1.1632x; 1.1632x over previous
//
#include <hip/hip_runtime.h>
#include <hip/hip_bf16.h>
#include <math.h>

#define B_ 8
#define L_ 1024
#define DM 256
#define DI 512
#define HD 32
#define NH 16
#define DS 128
#define CDIM 768
#define NZX 1280    // z + xBC cols (dt computed separately)
#define CH 256
#define NC 4
#define M_ (B_*L_)
#define EPSV 1e-5f

typedef short bf16x8 __attribute__((ext_vector_type(8)));
typedef float f32x4 __attribute__((ext_vector_type(4)));

// ---- workspace layout (float units) ----
#define OFF_ZX   0                         // M_*NZX bf16
#define SZ_ZX    (M_*NZX/2)
#define OFF_XC   (OFF_ZX+SZ_ZX)            // M_*CDIM bf16
#define SZ_XC    (M_*CDIM/2)
#define OFF_DT   (OFF_XC+SZ_XC)            // M_*NH fp32
#define SZ_DT    (M_*NH)
#define OFF_ACS  (OFF_DT+SZ_DT)
#define SZ_ACS   (B_*NC*NH*CH)
#define OFF_S0   (OFF_ACS+SZ_ACS)          // bf16 S0b
#define SZ_S0    (B_*NC*CH*CH/2)
#define OFF_ST   (OFF_S0+SZ_S0)            // bf16 states [bc][h][p][n]
#define SZ_ST    (B_*NC*NH*HD*DS/2)
#define OFF_Y    (OFF_ST+SZ_ST)            // M_*DI bf16
#define SZ_Y     (M_*DI/2)
#define OFF_YNB  (OFF_Y+SZ_Y)              // M_*DI bf16
#define SZ_YNB   (M_*DI/2)
#define OFF_XBF  (OFF_YNB+SZ_YNB)          // M_*DM bf16
#define SZ_XBF   (M_*DM/2)
#define OFF_WBF  (OFF_XBF+SZ_XBF)          // 1296*DM bf16
#define SZ_WBF   (1296*DM/2)
#define OFF_WOBF (OFF_WBF+SZ_WBF)          // DM*DI bf16
#define SZ_WOBF  (DM*DI/2)
#define OFF_GNP  (OFF_WOBF+SZ_WOBF)        // 64 float2 group accumulators
#define SZ_GNP   (64*2)
#define OFF_BT   (OFF_GNP+SZ_GNP)          // B^T: 32*128*256 bf16
#define SZ_BT    (32*128*256/2)
#define OFF_OUTB (OFF_BT+SZ_BT)            // pre-GN out bf16: M_*DM
#define SZ_OUTB  (M_*DM/2)

__device__ __forceinline__ ushort f2bf(float v) {
  __hip_bfloat16 h = __float2bfloat16(v);
  return *(ushort*)&h;
}
__device__ __forceinline__ float bf2f(ushort u) {
  return __uint_as_float(((unsigned int)u) << 16);
}

// ---------- fused prep: x transpose+cast, W casts, gnp zero, dt (exact fp32) ----------
__global__ __launch_bounds__(256) void k_prep(const float* __restrict__ x,
                                              const float* __restrict__ W_in,
                                              const float* __restrict__ W_out,
                                              const float* __restrict__ dt_bias,
                                              ushort* __restrict__ xbf,
                                              ushort* __restrict__ wbf,
                                              ushort* __restrict__ wobf,
                                              float2* __restrict__ gnp,
                                              float* __restrict__ dtb) {
  __shared__ float Ts[64][65];
  __shared__ float Xs[256][16];
  __shared__ float Ws[16][257];
  const int bid = blockIdx.x;
  const int t = threadIdx.x;
  if (bid < 512) {
    const int kt = bid & 3, lt = (bid >> 2) & 15, b = bid >> 6;
    const int k0 = kt*64, l0 = lt*64;
    for (int i = t; i < 4096; i += 256) {
      int kk = i>>6, ll = i&63;
      Ts[kk][ll] = x[(size_t)b*DM*L_ + (size_t)(k0+kk)*L_ + l0+ll];
    }
    __syncthreads();
    for (int i = t; i < 4096; i += 256) {
      int mm = i>>6, kk = i&63;
      xbf[(size_t)(b*L_ + l0+mm)*DM + k0+kk] = f2bf(Ts[kk][mm]);
    }
  } else if (bid < 512 + 1296) {
    int i = (bid-512)*256 + t;
    if (i < 1296*DM) wbf[i] = f2bf(W_in[i]);
  } else if (bid < 512 + 1296 + 512) {
    int i = (bid-512-1296)*256 + t;
    wobf[i] = f2bf(W_out[i]);
  } else if (bid == 2320) {
    if (t < 64) gnp[t] = make_float2(0.f, 0.f);
  } else {
    const int bm = (bid - 2321)*16;
    const int b = bm >> 10, l0 = bm & 1023;
    for (int i = t; i < 4096; i += 256) {
      int h = i>>8, k = i&255;
      Ws[h][k] = W_in[(size_t)(NZX+h)*DM + k];
    }
    for (int i = t; i < 4096; i += 256) {
      int k = i>>4, li = i&15;
      Xs[k][li] = x[(size_t)b*DM*L_ + (size_t)k*L_ + l0+li];
    }
    __syncthreads();
    const int h = t&15, li = t>>4;
    float acc = 0.f;
#pragma unroll 8
    for (int k = 0; k < 256; ++k) acc += Xs[k][li]*Ws[h][k];
    float v = acc + dt_bias[h];
    dtb[(size_t)bm*NH + t] = (v > 20.f) ? v : log1pf(expf(v));
  }
}

// ---------- in-proj GEMM (bf16 MFMA, 128x128 tile, double-buffered) ----------
__global__ __launch_bounds__(256) void k_gemm_in_mfma(const ushort* __restrict__ xbf,
                                                      const ushort* __restrict__ wbf,
                                                      ushort* __restrict__ zxb) {
  __shared__ ushort As[2][128*40];
  __shared__ ushort Bs[2][128*40];
  const int tid = threadIdx.x;
  const int n0 = blockIdx.x*128, m0 = blockIdx.y*128;
  const int wave = tid>>6, lane = tid&63;
  const int lr = lane&15, quad = lane>>4;
  f32x4 acc[2][8];
#pragma unroll
  for (int mi=0;mi<2;++mi)
#pragma unroll
    for (int ni=0;ni<8;++ni)
#pragma unroll
      for (int r=0;r<4;++r) acc[mi][ni][r] = 0.f;
  const int srow = tid>>1, sc = (tid&1)*16;
  auto LOAD = [&](int buf, int k0) {
    *(uint4*)&As[buf][srow*40 + sc]     = *(const uint4*)(xbf + (size_t)(m0+srow)*DM + k0 + sc);
    *(uint4*)&As[buf][srow*40 + sc + 8] = *(const uint4*)(xbf + (size_t)(m0+srow)*DM + k0 + sc + 8);
    *(uint4*)&Bs[buf][srow*40 + sc]     = *(const uint4*)(wbf + (size_t)(n0+srow)*DM + k0 + sc);
    *(uint4*)&Bs[buf][srow*40 + sc + 8] = *(const uint4*)(wbf + (size_t)(n0+srow)*DM + k0 + sc + 8);
  };
  LOAD(0, 0);
#pragma unroll
  for (int i = 0; i < 8; ++i) {
    __syncthreads();
    if (i < 7) LOAD((i+1)&1, (i+1)*32);
    const int cur = i&1;
    bf16x8 af[2], bfr[8];
    af[0] = *(const bf16x8*)&As[cur][(wave*32+lr)*40 + quad*8];
    af[1] = *(const bf16x8*)&As[cur][(wave*32+16+lr)*40 + quad*8];
#pragma unroll
    for (int ni=0;ni<8;++ni) bfr[ni] = *(const bf16x8*)&Bs[cur][(ni*16+lr)*40 + quad*8];
#pragma unroll
    for (int mi=0;mi<2;++mi)
#pragma unroll
      for (int ni=0;ni<8;++ni)
        acc[mi][ni] = __builtin_amdgcn_mfma_f32_16x16x32_bf16(af[mi], bfr[ni], acc[mi][ni], 0, 0, 0);
  }
#pragma unroll
  for (int mi=0;mi<2;++mi) {
    int m = m0 + wave*32 + mi*16 + quad*4;
#pragma unroll
    for (int ni=0;ni<8;++ni) {
      int n = n0 + ni*16 + lr;
#pragma unroll
      for (int r=0;r<4;++r) zxb[(size_t)(m+r)*NZX + n] = f2bf(acc[mi][ni][r]);
    }
  }
}

// ---------- conv4 + SiLU -> bf16 xcb (+ direct B^T write) ----------
__global__ __launch_bounds__(256) void k_conv(const ushort* __restrict__ zxb,
                                              const float* __restrict__ cw,
                                              const float* __restrict__ cb,
                                              ushort* __restrict__ xcb,
                                              ushort* __restrict__ btg) {
  const int j = blockIdx.x*256 + threadIdx.x;          // 0..767
  const int m8 = blockIdx.y*8;
  const int l0 = m8 & 1023;
  const int mb = m8 & ~1023;
  const float4 w = *(const float4*)&cw[j*4];
  const float bias = cb[j];
  float v[11];
#pragma unroll
  for (int i = 0; i < 11; ++i) {
    int ll = l0 - 3 + i;
    v[i] = (ll >= 0) ? bf2f(zxb[(size_t)(mb+ll)*NZX + DI + j]) : 0.f;
  }
  union { ushort u[8]; uint4 q; } res;
#pragma unroll
  for (int i = 0; i < 8; ++i) {
    float a = bias + w.x*v[i] + w.y*v[i+1] + w.z*v[i+2] + w.w*v[i+3];
    a = a / (1.f + expf(-a));
    res.u[i] = f2bf(a);
    xcb[(size_t)(mb+l0+i)*CDIM + j] = res.u[i];
  }
  if (j >= DI && j < DI+DS) {
    const int n = j - DI;
    const int bc = (mb >> 10)*NC + (l0 >> 8);
    const int lc = l0 & 255;
    *(uint4*)&btg[((size_t)bc*DS + n)*CH + lc] = res.q;
  }
}

// ---------- S0b = Cm·Bm^T (bf16 MFMA, lower-triangular tiles only) ----------
__global__ __launch_bounds__(256) void k_s0_mfma(const ushort* __restrict__ xcb,
                                                 ushort* __restrict__ S0b) {
  const int lt = blockIdx.x, st = blockIdx.y, bc = blockIdx.z;
  if (st > lt) return;
  const int base = bc*CH;
  const int t = threadIdx.x;
  const int wave = t>>6, lane = t&63, lr = lane&15, quad = lane>>4;
  const int l = lt*64 + wave*16 + lr;
  f32x4 acc[4];
#pragma unroll
  for (int nt = 0; nt < 4; ++nt)
#pragma unroll
    for (int r = 0; r < 4; ++r) acc[nt][r] = 0.f;
#pragma unroll
  for (int ks = 0; ks < 4; ++ks) {
    bf16x8 af = *(const bf16x8*)(xcb + (size_t)(base+l)*CDIM + (DI+DS) + ks*32 + quad*8);
#pragma unroll
    for (int nt = 0; nt < 4; ++nt) {
      bf16x8 bf = *(const bf16x8*)(xcb + (size_t)(base + st*64 + nt*16 + lr)*CDIM + DI + ks*32 + quad*8);
      acc[nt] = __builtin_amdgcn_mfma_f32_16x16x32_bf16(af, bf, acc[nt], 0, 0, 0);
    }
  }
#pragma unroll
  for (int nt = 0; nt < 4; ++nt)
#pragma unroll
    for (int r = 0; r < 4; ++r)
      S0b[((size_t)bc*CH + lt*64 + wave*16 + quad*4 + r)*CH + st*64 + nt*16 + lr] = f2bf(acc[nt][r]);
}

// ---------- per (b,c,h): cumsum + chunk states via MFMA -> bf16 stb[p][n] ----------
__global__ __launch_bounds__(256) void k_states_mfma(const ushort* __restrict__ xcb,
                                                     const ushort* __restrict__ btg,
                                                     const float* __restrict__ dtb,
                                                     const float* __restrict__ A_log,
                                                     float* __restrict__ acs_g,
                                                     ushort* __restrict__ stb) {
  __shared__ float acs[CH];
  __shared__ ushort Xw[32][264];
  const int t = threadIdx.x;
  const int bc = blockIdx.x, h = blockIdx.y;
  const int base = bc*CH;
  float dt_t = dtb[(size_t)(base+t)*NH + h];
  float An = -expf(A_log[h]);
  acs[t] = dt_t * An;
  __syncthreads();
  for (int off = 1; off < CH; off <<= 1) {
    float v = (t >= off) ? acs[t-off] : 0.f;
    __syncthreads();
    acs[t] += v;
    __syncthreads();
  }
  float alast = acs[CH-1];
  acs_g[((size_t)bc*NH + h)*CH + t] = acs[t];
  float w = expf(alast - acs[t]) * dt_t;
  {
    const ushort* xp = xcb + (size_t)(base+t)*CDIM + h*HD;
    ushort tmp[32];
    *(uint4*)&tmp[0]  = *(const uint4*)(xp);
    *(uint4*)&tmp[8]  = *(const uint4*)(xp+8);
    *(uint4*)&tmp[16] = *(const uint4*)(xp+16);
    *(uint4*)&tmp[24] = *(const uint4*)(xp+24);
#pragma unroll
    for (int p = 0; p < 32; ++p) Xw[p][t] = f2bf(bf2f(tmp[p]) * w);
  }
  __syncthreads();
  const int wave = t>>6, lane = t&63, lr = lane&15, quad = lane>>4;
  f32x4 acc[2][2];
#pragma unroll
  for (int mt=0;mt<2;++mt)
#pragma unroll
    for (int nt=0;nt<2;++nt)
#pragma unroll
      for (int r=0;r<4;++r) acc[mt][nt][r] = 0.f;
  const ushort* bp = btg + (size_t)bc*DS*CH;
#pragma unroll
  for (int k0 = 0; k0 < CH; k0 += 32) {
    bf16x8 a0 = *(const bf16x8*)&Xw[lr][k0 + quad*8];
    bf16x8 a1 = *(const bf16x8*)&Xw[16+lr][k0 + quad*8];
    bf16x8 b0 = *(const bf16x8*)(bp + (size_t)(wave*32 + lr)*CH + k0 + quad*8);
    bf16x8 b1 = *(const bf16x8*)(bp + (size_t)(wave*32 + 16 + lr)*CH + k0 + quad*8);
    acc[0][0] = __builtin_amdgcn_mfma_f32_16x16x32_bf16(a0, b0, acc[0][0], 0,0,0);
    acc[0][1] = __builtin_amdgcn_mfma_f32_16x16x32_bf16(a0, b1, acc[0][1], 0,0,0);
    acc[1][0] = __builtin_amdgcn_mfma_f32_16x16x32_bf16(a1, b0, acc[1][0], 0,0,0);
    acc[1][1] = __builtin_amdgcn_mfma_f32_16x16x32_bf16(a1, b1, acc[1][1], 0,0,0);
  }
  size_t sb = ((size_t)bc*NH + h)*HD*DS;
#pragma unroll
  for (int mt = 0; mt < 2; ++mt)
#pragma unroll
    for (int nt = 0; nt < 2; ++nt)
#pragma unroll
      for (int r = 0; r < 4; ++r)
        stb[sb + (size_t)(mt*16 + quad*4 + r)*DS + wave*32 + nt*16 + lr] = f2bf(acc[mt][nt][r]);
}

// ---------- Y = Y_diag + Y_off + D*xs (MFMA), inter-chunk scan fused -> bf16 ----------
__global__ __launch_bounds__(256) void k_y_mfma(const ushort* __restrict__ xcb,
    const float* __restrict__ dtb, const float* __restrict__ acs_g,
    const ushort* __restrict__ S0b, const ushort* __restrict__ stb,
    const float* __restrict__ Dp, ushort* __restrict__ Yb) {
  __shared__ ushort Xt[32][280];
  __shared__ float acs[CH];
  __shared__ float dts[CH];
  __shared__ float E8[CH];
  const int t = threadIdx.x;
  const int bc = blockIdx.x, h = blockIdx.y;
  const int base = bc*CH;
  const int cc = bc & 3, bc4 = bc & ~3;
  acs[t] = acs_g[((size_t)bc*NH + h)*CH + t];
  dts[t] = dtb[(size_t)(base+t)*NH + h];
  {
    const ushort* xp = xcb + (size_t)(base+t)*CDIM + h*HD;
    ushort tmp[32];
    *(uint4*)&tmp[0]  = *(const uint4*)(xp);
    *(uint4*)&tmp[8]  = *(const uint4*)(xp+8);
    *(uint4*)&tmp[16] = *(const uint4*)(xp+16);
    *(uint4*)&tmp[24] = *(const uint4*)(xp+24);
#pragma unroll
    for (int p = 0; p < 32; ++p) Xt[p][t] = tmp[p];
  }
  __syncthreads();
  E8[t] = expf(acs[t & ~7] - acs[t]) * dts[t];
  __syncthreads();
  const int wave = t>>6, lane = t&63, lr = lane&15, quad = lane>>4;
  f32x4 acc[4][2];
#pragma unroll
  for (int mt=0;mt<4;++mt)
#pragma unroll
    for (int nt=0;nt<2;++nt)
#pragma unroll
      for (int r=0;r<4;++r) acc[mt][nt][r] = 0.f;
  // ---- Y_off: C @ prev^T, prev reconstructed from prior chunks ----
  if (cc > 0) {
    float fj[3];
    {
      float cum = 0.f;
      for (int j = cc-1; j >= 0; --j) {
        fj[j] = expf(cum);
        cum += acs_g[((size_t)(bc4+j)*NH + h)*CH + (CH-1)];
      }
    }
#pragma unroll
    for (int ks = 0; ks < 4; ++ks) {
      bf16x8 bfr[2];
#pragma unroll
      for (int nt = 0; nt < 2; ++nt) {
        float P[8];
#pragma unroll
        for (int jj = 0; jj < 8; ++jj) P[jj] = 0.f;
        for (int j = 0; j < cc; ++j) {
          bf16x8 sv = *(const bf16x8*)(stb + ((size_t)(bc4+j)*NH + h)*HD*DS
                                       + (size_t)(nt*16+lr)*DS + ks*32 + quad*8);
#pragma unroll
          for (int jj = 0; jj < 8; ++jj) P[jj] += fj[j]*bf2f((ushort)sv[jj]);
        }
        bf16x8 bb;
#pragma unroll
        for (int jj = 0; jj < 8; ++jj) bb[jj] = (short)f2bf(P[jj]);
        bfr[nt] = bb;
      }
#pragma unroll
      for (int mt = 0; mt < 4; ++mt) {
        int l = wave*64 + mt*16 + lr;
        bf16x8 af = *(const bf16x8*)(xcb + (size_t)(base+l)*CDIM + (DI+DS) + ks*32 + quad*8);
        acc[mt][0] = __builtin_amdgcn_mfma_f32_16x16x32_bf16(af, bfr[0], acc[mt][0], 0,0,0);
        acc[mt][1] = __builtin_amdgcn_mfma_f32_16x16x32_bf16(af, bfr[1], acc[mt][1], 0,0,0);
      }
    }
#pragma unroll
    for (int mt = 0; mt < 4; ++mt)
#pragma unroll
      for (int r = 0; r < 4; ++r) {
        float e = expf(acs[wave*64 + mt*16 + quad*4 + r]);
        acc[mt][0][r] *= e;
        acc[mt][1][r] *= e;
      }
  }
  // ---- Y_diag ----
  float al[4];
#pragma unroll
  for (int mt = 0; mt < 4; ++mt) al[mt] = acs[wave*64 + mt*16 + lr];
  const int km3 = 2*wave + 1;
  for (int ks = 0; ks <= km3; ++ks) {
    const int sq = ks*32 + quad*8;
    const float as0 = acs[sq];
    const float4 e0 = *(const float4*)&E8[sq];
    const float4 e1 = *(const float4*)&E8[sq+4];
    const bf16x8 xb0 = *(const bf16x8*)&Xt[lr][sq];
    const bf16x8 xb1 = *(const bf16x8*)&Xt[16+lr][sq];
    const float ev[8] = {e0.x,e0.y,e0.z,e0.w,e1.x,e1.y,e1.z,e1.w};
#pragma unroll
    for (int mt = 0; mt < 4; ++mt) {
      if (ks > ((wave*64 + mt*16 + 15) >> 5)) continue;
      const int l = wave*64 + mt*16 + lr;
      const bf16x8 sb = *(const bf16x8*)(S0b + ((size_t)bc*CH + l)*CH + sq);
      const float el = expf(al[mt] - as0);
      bf16x8 mf;
#pragma unroll
      for (int j = 0; j < 8; ++j) {
        float v = (sq + j <= l) ? bf2f((ushort)sb[j]) * el * ev[j] : 0.f;
        mf[j] = (short)f2bf(v);
      }
      acc[mt][0] = __builtin_amdgcn_mfma_f32_16x16x32_bf16(mf, xb0, acc[mt][0], 0,0,0);
      acc[mt][1] = __builtin_amdgcn_mfma_f32_16x16x32_bf16(mf, xb1, acc[mt][1], 0,0,0);
    }
  }
  const float dph = Dp[h];
#pragma unroll
  for (int mt = 0; mt < 4; ++mt) {
    const int lb = wave*64 + mt*16 + quad*4;
#pragma unroll
    for (int nt = 0; nt < 2; ++nt) {
      const int p = nt*16 + lr;
#pragma unroll
      for (int r = 0; r < 4; ++r) {
        float xv = bf2f(Xt[p][lb+r]);
        Yb[(size_t)(base+lb+r)*DI + h*HD + p] = f2bf(acc[mt][nt][r] + dph*xv);
      }
    }
  }
}

// ---------- gate + RMSNorm, wave-per-row, no barriers ----------
__global__ __launch_bounds__(256) void k_rms(const ushort* __restrict__ zxb,
                                             const ushort* __restrict__ Yb,
                                             const float* __restrict__ rw,
                                             ushort* __restrict__ yn) {
  const int m = blockIdx.x*4 + (threadIdx.x>>6);
  const int lane = threadIdx.x & 63;
  const int c0 = lane*8;
  bf16x8 zv = *(const bf16x8*)(zxb + (size_t)m*NZX + c0);
  bf16x8 yv = *(const bf16x8*)(Yb  + (size_t)m*DI  + c0);
  float y[8];
  float ss = 0.f;
#pragma unroll
  for (int j = 0; j < 8; ++j) {
    float z = bf2f((ushort)zv[j]);
    y[j] = bf2f((ushort)yv[j]) * z / (1.f + expf(-z));
    ss += y[j]*y[j];
  }
#pragma unroll
  for (int off = 1; off < 64; off <<= 1) ss += __shfl_xor(ss, off);
  const float inv = rsqrtf(ss * (1.f/DI) + EPSV);
  float4 w0 = *(const float4*)&rw[c0];
  float4 w1 = *(const float4*)&rw[c0+4];
  const float wv[8] = {w0.x,w0.y,w0.z,w0.w,w1.x,w1.y,w1.z,w1.w};
  union { ushort u[8]; uint4 q; } pk;
#pragma unroll
  for (int j = 0; j < 8; ++j) pk.u[j] = f2bf(y[j] * inv * wv[j]);
  *(uint4*)(yn + (size_t)m*DI + c0) = pk.q;
}

// ---------- out-proj GEMM (bf16 MFMA, double-buffered) -> bf16 outb + GN partials ----------
__global__ __launch_bounds__(256) void k_gemm_out_mfma(const ushort* __restrict__ ynbf,
                                                       const ushort* __restrict__ wobf,
                                                       ushort* __restrict__ outb,
                                                       float2* __restrict__ gnp) {
  __shared__ ushort As[2][128*40];
  __shared__ ushort Bs[2][64*40];
  const int tid = threadIdx.x;
  const int n0 = blockIdx.x*64, m0 = blockIdx.y*128;
  const int wave = tid>>6, lane = tid&63;
  const int lr = lane&15, quad = lane>>4;
  f32x4 acc[2][4];
#pragma unroll
  for (int mi=0;mi<2;++mi)
#pragma unroll
    for (int ni=0;ni<4;++ni)
#pragma unroll
      for (int r=0;r<4;++r) acc[mi][ni][r] = 0.f;
  const int srow = tid>>1, sc = (tid&1)*16;
  const int brow = tid>>2, bcol = (tid&3)*8;
  auto LOAD = [&](int buf, int k0) {
    *(uint4*)&As[buf][srow*40 + sc]     = *(const uint4*)(ynbf + (size_t)(m0+srow)*DI + k0 + sc);
    *(uint4*)&As[buf][srow*40 + sc + 8] = *(const uint4*)(ynbf + (size_t)(m0+srow)*DI + k0 + sc + 8);
    *(uint4*)&Bs[buf][brow*40 + bcol]   = *(const uint4*)(wobf + (size_t)(n0+brow)*DI + k0 + bcol);
  };
  LOAD(0, 0);
#pragma unroll
  for (int i = 0; i < 16; ++i) {
    __syncthreads();
    if (i < 15) LOAD((i+1)&1, (i+1)*32);
    const int cur = i&1;
    bf16x8 af[2], bfr[4];
    af[0] = *(const bf16x8*)&As[cur][(wave*32+lr)*40 + quad*8];
    af[1] = *(const bf16x8*)&As[cur][(wave*32+16+lr)*40 + quad*8];
#pragma unroll
    for (int ni=0;ni<4;++ni) bfr[ni] = *(const bf16x8*)&Bs[cur][(ni*16+lr)*40 + quad*8];
#pragma unroll
    for (int mi=0;mi<2;++mi)
#pragma unroll
      for (int ni=0;ni<4;++ni)
        acc[mi][ni] = __builtin_amdgcn_mfma_f32_16x16x32_bf16(af[mi], bfr[ni], acc[mi][ni], 0, 0, 0);
  }
  const int b = m0 >> 10, l0 = m0 & 1023;
  float s0=0.f, ss0=0.f, s1=0.f, ss1=0.f;
#pragma unroll
  for (int mi=0;mi<2;++mi) {
    int lb = l0 + wave*32 + mi*16 + quad*4;
#pragma unroll
    for (int ni=0;ni<4;++ni) {
      int n = n0 + ni*16 + lr;
      union { ushort u[4]; uint2 q; } pk;
#pragma unroll
      for (int r=0;r<4;++r) pk.u[r] = f2bf(acc[mi][ni][r]);
      *(uint2*)&outb[(size_t)b*DM*L_ + (size_t)n*L_ + lb] = pk.q;
      float ps = acc[mi][ni][0]+acc[mi][ni][1]+acc[mi][ni][2]+acc[mi][ni][3];
      float pq = acc[mi][ni][0]*acc[mi][ni][0]+acc[mi][ni][1]*acc[mi][ni][1]
               + acc[mi][ni][2]*acc[mi][ni][2]+acc[mi][ni][3]*acc[mi][ni][3];
      if (ni < 2) { s0 += ps; ss0 += pq; } else { s1 += ps; ss1 += pq; }
    }
  }
#pragma unroll
  for (int off = 32; off > 0; off >>= 1) {
    s0 += __shfl_down(s0, off); ss0 += __shfl_down(ss0, off);
    s1 += __shfl_down(s1, off); ss1 += __shfl_down(ss1, off);
  }
  __shared__ float red[4][4];
  if (lane == 0) { red[wave][0]=s0; red[wave][1]=ss0; red[wave][2]=s1; red[wave][3]=ss1; }
  __syncthreads();
  if (tid == 0) {
    float S0=0,Q0=0,S1=0,Q1=0;
#pragma unroll
    for (int wv2 = 0; wv2 < 4; ++wv2) { S0+=red[wv2][0]; Q0+=red[wv2][1]; S1+=red[wv2][2]; Q1+=red[wv2][3]; }
    int g0 = b*8 + (n0>>5);
    atomicAdd(&gnp[g0].x, S0);   atomicAdd(&gnp[g0].y, Q0);
    atomicAdd(&gnp[g0+1].x, S1); atomicAdd(&gnp[g0+1].y, Q1);
  }
}

// ---------- GroupNorm apply + Mish: bf16 in, fp32 out ----------
__global__ __launch_bounds__(256) void k_gn_apply(const float2* __restrict__ gnp,
                                                  const float* __restrict__ gw,
                                                  const float* __restrict__ gb,
                                                  const ushort* __restrict__ ob,
                                                  float* __restrict__ o) {
  const int ch = blockIdx.x & 255, b = blockIdx.x >> 8;
  const int t = threadIdx.x;
  float2 p = gnp[b*8 + (ch>>5)];
  const float mean = p.x * (1.f/(32.f*L_));
  const float var  = p.y * (1.f/(32.f*L_)) - mean*mean;
  const float inv  = rsqrtf(var + EPSV);
  const float w = gw[ch], bb = gb[ch];
  size_t base = (size_t)blockIdx.x * L_;
  ushort4 v = *(const ushort4*)&ob[base + t*4];
  float r[4] = {bf2f(v.x), bf2f(v.y), bf2f(v.z), bf2f(v.w)};
#pragma unroll
  for (int j = 0; j < 4; ++j) {
    float u = (r[j] - mean) * inv * w + bb;
    float m;
    if (u > 15.f) m = u;
    else {
      float e = expf(u);
      float a = 1.f + e;
      float a2 = a*a;
      m = u * (a2 - 1.f) / (a2 + 1.f);
    }
    r[j] = m;
  }
  *(float4*)&o[base + t*4] = make_float4(r[0], r[1], r[2], r[3]);
}

extern "C" void kernel_launch(void* const* d_in, const int* in_sizes, int n_in,
                              void* d_out, int out_size, void* d_ws, size_t ws_size,
                              hipStream_t stream) {
  const float* x       = (const float*)d_in[0];
  const float* W_in    = (const float*)d_in[1];
  const float* conv_w  = (const float*)d_in[2];
  const float* conv_b  = (const float*)d_in[3];
  const float* dt_bias = (const float*)d_in[4];
  const float* A_log   = (const float*)d_in[5];
  const float* Dp      = (const float*)d_in[6];
  const float* rms_w   = (const float*)d_in[7];
  const float* W_out   = (const float*)d_in[8];
  const float* gn_w    = (const float*)d_in[9];
  const float* gn_b    = (const float*)d_in[10];
  float* out = (float*)d_out;
  float* ws  = (float*)d_ws;

  ushort* zxb   = (ushort*)(ws + OFF_ZX);
  ushort* xcb   = (ushort*)(ws + OFF_XC);
  float*  dtb   = ws + OFF_DT;
  float*  acs   = ws + OFF_ACS;
  ushort* S0b   = (ushort*)(ws + OFF_S0);
  ushort* stb   = (ushort*)(ws + OFF_ST);
  ushort* Ybb   = (ushort*)(ws + OFF_Y);
  ushort* ynbf  = (ushort*)(ws + OFF_YNB);
  ushort* xbf   = (ushort*)(ws + OFF_XBF);
  ushort* wbf   = (ushort*)(ws + OFF_WBF);
  ushort* wobf  = (ushort*)(ws + OFF_WOBF);
  float2* gnp   = (float2*)(ws + OFF_GNP);
  ushort* btg   = (ushort*)(ws + OFF_BT);
  ushort* outb  = (ushort*)(ws + OFF_OUTB);

  k_prep         <<<dim3(512+1296+512+1+512), 256, 0, stream>>>(x, W_in, W_out, dt_bias,
                                                                xbf, wbf, wobf, gnp, dtb);
  k_gemm_in_mfma <<<dim3(NZX/128, M_/128), 256, 0, stream>>>(xbf, wbf, zxb);
  k_conv         <<<dim3(3, M_/8), 256, 0, stream>>>(zxb, conv_w, conv_b, xcb, btg);
  k_s0_mfma      <<<dim3(4, 4, B_*NC), 256, 0, stream>>>(xcb, S0b);
  k_states_mfma  <<<dim3(B_*NC, NH), 256, 0, stream>>>(xcb, btg, dtb, A_log, acs, stb);
  k_y_mfma       <<<dim3(B_*NC, NH), 256, 0, stream>>>(xcb, dtb, acs, S0b, stb, Dp, Ybb);
  k_rms          <<<dim3(M_/4), 256, 0, stream>>>(zxb, Ybb, rms_w, ynbf);
  k_gemm_out_mfma<<<dim3(DM/64, M_/128), 256, 0, stream>>>(ynbf, wobf, outb, gnp);
  k_gn_apply     <<<dim3(B_*DM), 256, 0, stream>>>(gnp, gn_w, gn_b, outb, out);
}

// Round 11
// 184.590 us; speedup vs baseline: 1.2008x; 1.0323x over previous
//
#include <hip/hip_runtime.h>
#include <hip/hip_bf16.h>
#include <math.h>

#define B_ 8
#define L_ 1024
#define DM 256
#define DI 512
#define HD 32
#define NH 16
#define DS 128
#define CDIM 768
#define NZX 1280
#define CH 256
#define NC 4
#define M_ (B_*L_)
#define EPSV 1e-5f

typedef short bf16x8 __attribute__((ext_vector_type(8)));
typedef float f32x4 __attribute__((ext_vector_type(4)));

#define OFF_ZX   0
#define SZ_ZX    (M_*NZX/2)
#define OFF_XC   (OFF_ZX+SZ_ZX)
#define SZ_XC    (M_*CDIM/2)
#define OFF_DTP  (OFF_XC+SZ_XC)
#define SZ_DTP   (4*M_*NH)
#define OFF_ACS  (OFF_DTP+SZ_DTP)
#define SZ_ACS   (B_*NC*NH*CH)
#define OFF_S0   (OFF_ACS+SZ_ACS)
#define SZ_S0    (B_*NC*CH*CH/2)
#define OFF_ST   (OFF_S0+SZ_S0)
#define SZ_ST    (B_*NC*NH*HD*DS/2)
#define OFF_Y    (OFF_ST+SZ_ST)
#define SZ_Y     (M_*DI/2)
#define OFF_YNB  (OFF_Y+SZ_Y)
#define SZ_YNB   (M_*DI/2)
#define OFF_XBF  (OFF_YNB+SZ_YNB)
#define SZ_XBF   (M_*DM/2)
#define OFF_WBF  (OFF_XBF+SZ_XBF)
#define SZ_WBF   (1296*DM/2)
#define OFF_WOBF (OFF_WBF+SZ_WBF)
#define SZ_WOBF  (DM*DI/2)
#define OFF_GNP  (OFF_WOBF+SZ_WOBF)
#define SZ_GNP   (64*2)
#define OFF_BT   (OFF_GNP+SZ_GNP)
#define SZ_BT    (32*128*256/2)
#define OFF_OUTB (OFF_BT+SZ_BT)
#define SZ_OUTB  (M_*DM/2)

__device__ __forceinline__ ushort f2bf(float v) {
  __hip_bfloat16 h = __float2bfloat16(v);
  return *(ushort*)&h;
}
__device__ __forceinline__ float bf2f(ushort u) {
  return __uint_as_float(((unsigned int)u) << 16);
}
__device__ __forceinline__ float dt_load(const float* __restrict__ dtp, size_t di) {
  float s = dtp[di] + dtp[(size_t)M_*NH + di] + dtp[2*(size_t)M_*NH + di] + dtp[3*(size_t)M_*NH + di];
  return (s > 20.f) ? s : log1pf(expf(s));
}

// ---------- fused prep: x transpose+cast + dt partials (bias folded), W casts, gnp zero ----------
__global__ __launch_bounds__(256) void k_prep(const float* __restrict__ x,
                                              const float* __restrict__ W_in,
                                              const float* __restrict__ W_out,
                                              const float* __restrict__ dt_bias,
                                              ushort* __restrict__ xbf,
                                              ushort* __restrict__ wbf,
                                              ushort* __restrict__ wobf,
                                              float2* __restrict__ gnp,
                                              float* __restrict__ dtp) {
  __shared__ float Ts[64][65];
  __shared__ float Wd[16][65];
  const int bid = blockIdx.x;
  const int t = threadIdx.x;
  if (bid < 512) {
    const int kt = bid & 3, lt2 = (bid >> 2) & 15, b = bid >> 6;
    const int k0 = kt*64, l0 = lt2*64;
    for (int i = t; i < 4096; i += 256) {
      int kk = i>>6, ll = i&63;
      Ts[kk][ll] = x[(size_t)b*DM*L_ + (size_t)(k0+kk)*L_ + l0+ll];
    }
    for (int i = t; i < 1024; i += 256) {
      int h = i>>6, kk = i&63;
      Wd[h][kk] = W_in[(size_t)(NZX+h)*DM + k0+kk];
    }
    __syncthreads();
    for (int i = t; i < 4096; i += 256) {
      int mm = i>>6, kk = i&63;
      xbf[(size_t)(b*L_ + l0+mm)*DM + k0+kk] = f2bf(Ts[kk][mm]);
    }
    const int h = t&15, lg = t>>4;
    const float bias = (kt == 0) ? dt_bias[h] : 0.f;
#pragma unroll
    for (int c = 0; c < 4; ++c) {
      const int ll = lg + c*16;
      float acc = bias;
#pragma unroll 8
      for (int kk = 0; kk < 64; ++kk) acc += Wd[h][kk]*Ts[kk][ll];
      dtp[(size_t)kt*M_*NH + (size_t)(b*L_ + l0+ll)*NH + h] = acc;
    }
  } else if (bid < 512 + 1296) {
    int i = (bid-512)*256 + t;
    if (i < 1296*DM) wbf[i] = f2bf(W_in[i]);
  } else if (bid < 512 + 1296 + 512) {
    int i = (bid-512-1296)*256 + t;
    wobf[i] = f2bf(W_out[i]);
  } else {
    if (t < 64) gnp[t] = make_float2(0.f, 0.f);
  }
}

// ---------- in-proj GEMM (bf16 MFMA, 128x128 tile, double-buffered) ----------
__global__ __launch_bounds__(256) void k_gemm_in_mfma(const ushort* __restrict__ xbf,
                                                      const ushort* __restrict__ wbf,
                                                      ushort* __restrict__ zxb) {
  __shared__ ushort As[2][128*40];
  __shared__ ushort Bs[2][128*40];
  const int tid = threadIdx.x;
  const int n0 = blockIdx.x*128, m0 = blockIdx.y*128;
  const int wave = tid>>6, lane = tid&63;
  const int lr = lane&15, quad = lane>>4;
  f32x4 acc[2][8];
#pragma unroll
  for (int mi=0;mi<2;++mi)
#pragma unroll
    for (int ni=0;ni<8;++ni)
#pragma unroll
      for (int r=0;r<4;++r) acc[mi][ni][r] = 0.f;
  const int srow = tid>>1, sc = (tid&1)*16;
  auto LOAD = [&](int buf, int k0) {
    *(uint4*)&As[buf][srow*40 + sc]     = *(const uint4*)(xbf + (size_t)(m0+srow)*DM + k0 + sc);
    *(uint4*)&As[buf][srow*40 + sc + 8] = *(const uint4*)(xbf + (size_t)(m0+srow)*DM + k0 + sc + 8);
    *(uint4*)&Bs[buf][srow*40 + sc]     = *(const uint4*)(wbf + (size_t)(n0+srow)*DM + k0 + sc);
    *(uint4*)&Bs[buf][srow*40 + sc + 8] = *(const uint4*)(wbf + (size_t)(n0+srow)*DM + k0 + sc + 8);
  };
  LOAD(0, 0);
#pragma unroll
  for (int i = 0; i < 8; ++i) {
    __syncthreads();
    if (i < 7) LOAD((i+1)&1, (i+1)*32);
    const int cur = i&1;
    bf16x8 af[2], bfr[8];
    af[0] = *(const bf16x8*)&As[cur][(wave*32+lr)*40 + quad*8];
    af[1] = *(const bf16x8*)&As[cur][(wave*32+16+lr)*40 + quad*8];
#pragma unroll
    for (int ni=0;ni<8;++ni) bfr[ni] = *(const bf16x8*)&Bs[cur][(ni*16+lr)*40 + quad*8];
#pragma unroll
    for (int mi=0;mi<2;++mi)
#pragma unroll
      for (int ni=0;ni<8;++ni)
        acc[mi][ni] = __builtin_amdgcn_mfma_f32_16x16x32_bf16(af[mi], bfr[ni], acc[mi][ni], 0, 0, 0);
  }
#pragma unroll
  for (int mi=0;mi<2;++mi) {
    int m = m0 + wave*32 + mi*16 + quad*4;
#pragma unroll
    for (int ni=0;ni<8;++ni) {
      int n = n0 + ni*16 + lr;
#pragma unroll
      for (int r=0;r<4;++r) zxb[(size_t)(m+r)*NZX + n] = f2bf(acc[mi][ni][r]);
    }
  }
}

// ---------- conv4 + SiLU -> bf16 xcb (+ direct B^T write) ----------
__global__ __launch_bounds__(256) void k_conv(const ushort* __restrict__ zxb,
                                              const float* __restrict__ cw,
                                              const float* __restrict__ cb,
                                              ushort* __restrict__ xcb,
                                              ushort* __restrict__ btg) {
  const int j = blockIdx.x*256 + threadIdx.x;
  const int m8 = blockIdx.y*8;
  const int l0 = m8 & 1023;
  const int mb = m8 & ~1023;
  const float4 w = *(const float4*)&cw[j*4];
  const float bias = cb[j];
  float v[11];
#pragma unroll
  for (int i = 0; i < 11; ++i) {
    int ll = l0 - 3 + i;
    v[i] = (ll >= 0) ? bf2f(zxb[(size_t)(mb+ll)*NZX + DI + j]) : 0.f;
  }
  union { ushort u[8]; uint4 q; } res;
#pragma unroll
  for (int i = 0; i < 8; ++i) {
    float a = bias + w.x*v[i] + w.y*v[i+1] + w.z*v[i+2] + w.w*v[i+3];
    a = a / (1.f + expf(-a));
    res.u[i] = f2bf(a);
    xcb[(size_t)(mb+l0+i)*CDIM + j] = res.u[i];
  }
  if (j >= DI && j < DI+DS) {
    const int n = j - DI;
    const int bc = (mb >> 10)*NC + (l0 >> 8);
    const int lc = l0 & 255;
    *(uint4*)&btg[((size_t)bc*DS + n)*CH + lc] = res.q;
  }
}

// ---------- merged: S0 lower-tri tiles (role<10) + chunk states (role>=10) ----------
__global__ __launch_bounds__(256) void k_s0st(const ushort* __restrict__ xcb,
                                              const ushort* __restrict__ btg,
                                              const float* __restrict__ dtp,
                                              const float* __restrict__ A_log,
                                              float* __restrict__ acs_g,
                                              ushort* __restrict__ stb,
                                              ushort* __restrict__ S0b) {
  __shared__ float acs[CH];
  __shared__ ushort Xw[32][264];
  const int role = blockIdx.x;
  const int bc = blockIdx.y;
  const int base = bc*CH;
  const int t = threadIdx.x;
  const int wave = t>>6, lane = t&63, lr = lane&15, quad = lane>>4;
  if (role < 10) {
    const int lt = (role>=6) ? 3 : (role>=3) ? 2 : (role>=1) ? 1 : 0;
    const int st = role - lt*(lt+1)/2;
    const int l = lt*64 + wave*16 + lr;
    f32x4 acc[4];
#pragma unroll
    for (int nt = 0; nt < 4; ++nt)
#pragma unroll
      for (int r = 0; r < 4; ++r) acc[nt][r] = 0.f;
#pragma unroll
    for (int ks = 0; ks < 4; ++ks) {
      bf16x8 af = *(const bf16x8*)(xcb + (size_t)(base+l)*CDIM + (DI+DS) + ks*32 + quad*8);
#pragma unroll
      for (int nt = 0; nt < 4; ++nt) {
        bf16x8 bf = *(const bf16x8*)(xcb + (size_t)(base + st*64 + nt*16 + lr)*CDIM + DI + ks*32 + quad*8);
        acc[nt] = __builtin_amdgcn_mfma_f32_16x16x32_bf16(af, bf, acc[nt], 0, 0, 0);
      }
    }
#pragma unroll
    for (int nt = 0; nt < 4; ++nt)
#pragma unroll
      for (int r = 0; r < 4; ++r)
        S0b[((size_t)bc*CH + lt*64 + wave*16 + quad*4 + r)*CH + st*64 + nt*16 + lr] = f2bf(acc[nt][r]);
    return;
  }
  const int h = role - 10;
  float dt_t = dt_load(dtp, (size_t)(base+t)*NH + h);
  float An = -expf(A_log[h]);
  acs[t] = dt_t * An;
  __syncthreads();
  for (int off = 1; off < CH; off <<= 1) {
    float v = (t >= off) ? acs[t-off] : 0.f;
    __syncthreads();
    acs[t] += v;
    __syncthreads();
  }
  float alast = acs[CH-1];
  acs_g[((size_t)bc*NH + h)*CH + t] = acs[t];
  float w = expf(alast - acs[t]) * dt_t;
  {
    const ushort* xp = xcb + (size_t)(base+t)*CDIM + h*HD;
    ushort tmp[32];
    *(uint4*)&tmp[0]  = *(const uint4*)(xp);
    *(uint4*)&tmp[8]  = *(const uint4*)(xp+8);
    *(uint4*)&tmp[16] = *(const uint4*)(xp+16);
    *(uint4*)&tmp[24] = *(const uint4*)(xp+24);
#pragma unroll
    for (int p = 0; p < 32; ++p) Xw[p][t] = f2bf(bf2f(tmp[p]) * w);
  }
  __syncthreads();
  f32x4 acc2[2][2];
#pragma unroll
  for (int mt=0;mt<2;++mt)
#pragma unroll
    for (int nt=0;nt<2;++nt)
#pragma unroll
      for (int r=0;r<4;++r) acc2[mt][nt][r] = 0.f;
  const ushort* bp = btg + (size_t)bc*DS*CH;
#pragma unroll
  for (int k0 = 0; k0 < CH; k0 += 32) {
    bf16x8 a0 = *(const bf16x8*)&Xw[lr][k0 + quad*8];
    bf16x8 a1 = *(const bf16x8*)&Xw[16+lr][k0 + quad*8];
    bf16x8 b0 = *(const bf16x8*)(bp + (size_t)(wave*32 + lr)*CH + k0 + quad*8);
    bf16x8 b1 = *(const bf16x8*)(bp + (size_t)(wave*32 + 16 + lr)*CH + k0 + quad*8);
    acc2[0][0] = __builtin_amdgcn_mfma_f32_16x16x32_bf16(a0, b0, acc2[0][0], 0,0,0);
    acc2[0][1] = __builtin_amdgcn_mfma_f32_16x16x32_bf16(a0, b1, acc2[0][1], 0,0,0);
    acc2[1][0] = __builtin_amdgcn_mfma_f32_16x16x32_bf16(a1, b0, acc2[1][0], 0,0,0);
    acc2[1][1] = __builtin_amdgcn_mfma_f32_16x16x32_bf16(a1, b1, acc2[1][1], 0,0,0);
  }
  size_t sb = ((size_t)bc*NH + h)*HD*DS;
#pragma unroll
  for (int mt = 0; mt < 2; ++mt)
#pragma unroll
    for (int nt = 0; nt < 2; ++nt)
#pragma unroll
      for (int r = 0; r < 4; ++r)
        stb[sb + (size_t)(mt*16 + quad*4 + r)*DS + wave*32 + nt*16 + lr] = f2bf(acc2[mt][nt][r]);
}

// ---------- Y = Y_diag + Y_off + D*xs (MFMA), inter-chunk scan fused -> bf16 ----------
__global__ __launch_bounds__(256) void k_y_mfma(const ushort* __restrict__ xcb,
    const float* __restrict__ dtp, const float* __restrict__ acs_g,
    const ushort* __restrict__ S0b, const ushort* __restrict__ stb,
    const float* __restrict__ Dp, ushort* __restrict__ Yb) {
  __shared__ ushort Xt[32][280];
  __shared__ float acs[CH];
  __shared__ float E8[CH];
  const int t = threadIdx.x;
  const int bc = blockIdx.x, h = blockIdx.y;
  const int base = bc*CH;
  const int cc = bc & 3, bc4 = bc & ~3;
  acs[t] = acs_g[((size_t)bc*NH + h)*CH + t];
  const float dts_t = dt_load(dtp, (size_t)(base+t)*NH + h);
  {
    const ushort* xp = xcb + (size_t)(base+t)*CDIM + h*HD;
    ushort tmp[32];
    *(uint4*)&tmp[0]  = *(const uint4*)(xp);
    *(uint4*)&tmp[8]  = *(const uint4*)(xp+8);
    *(uint4*)&tmp[16] = *(const uint4*)(xp+16);
    *(uint4*)&tmp[24] = *(const uint4*)(xp+24);
#pragma unroll
    for (int p = 0; p < 32; ++p) Xt[p][t] = tmp[p];
  }
  __syncthreads();
  E8[t] = expf(acs[t & ~7] - acs[t]) * dts_t;
  __syncthreads();
  const int wave = t>>6, lane = t&63, lr = lane&15, quad = lane>>4;
  f32x4 acc[4][2];
#pragma unroll
  for (int mt=0;mt<4;++mt)
#pragma unroll
    for (int nt=0;nt<2;++nt)
#pragma unroll
      for (int r=0;r<4;++r) acc[mt][nt][r] = 0.f;
  if (cc > 0) {
    float fj[3];
    {
      float cum = 0.f;
      for (int j = cc-1; j >= 0; --j) {
        fj[j] = expf(cum);
        cum += acs_g[((size_t)(bc4+j)*NH + h)*CH + (CH-1)];
      }
    }
#pragma unroll
    for (int ks = 0; ks < 4; ++ks) {
      bf16x8 bfr[2];
#pragma unroll
      for (int nt = 0; nt < 2; ++nt) {
        float P[8];
#pragma unroll
        for (int jj = 0; jj < 8; ++jj) P[jj] = 0.f;
        for (int j = 0; j < cc; ++j) {
          bf16x8 sv = *(const bf16x8*)(stb + ((size_t)(bc4+j)*NH + h)*HD*DS
                                       + (size_t)(nt*16+lr)*DS + ks*32 + quad*8);
#pragma unroll
          for (int jj = 0; jj < 8; ++jj) P[jj] += fj[j]*bf2f((ushort)sv[jj]);
        }
        bf16x8 bb;
#pragma unroll
        for (int jj = 0; jj < 8; ++jj) bb[jj] = (short)f2bf(P[jj]);
        bfr[nt] = bb;
      }
#pragma unroll
      for (int mt = 0; mt < 4; ++mt) {
        int l = wave*64 + mt*16 + lr;
        bf16x8 af = *(const bf16x8*)(xcb + (size_t)(base+l)*CDIM + (DI+DS) + ks*32 + quad*8);
        acc[mt][0] = __builtin_amdgcn_mfma_f32_16x16x32_bf16(af, bfr[0], acc[mt][0], 0,0,0);
        acc[mt][1] = __builtin_amdgcn_mfma_f32_16x16x32_bf16(af, bfr[1], acc[mt][1], 0,0,0);
      }
    }
#pragma unroll
    for (int mt = 0; mt < 4; ++mt)
#pragma unroll
      for (int r = 0; r < 4; ++r) {
        float e = expf(acs[wave*64 + mt*16 + quad*4 + r]);
        acc[mt][0][r] *= e;
        acc[mt][1][r] *= e;
      }
  }
  float al[4];
#pragma unroll
  for (int mt = 0; mt < 4; ++mt) al[mt] = acs[wave*64 + mt*16 + lr];
  const int km3 = 2*wave + 1;
  for (int ks = 0; ks <= km3; ++ks) {
    const int sq = ks*32 + quad*8;
    const float as0 = acs[sq];
    const float4 e0 = *(const float4*)&E8[sq];
    const float4 e1 = *(const float4*)&E8[sq+4];
    const bf16x8 xb0 = *(const bf16x8*)&Xt[lr][sq];
    const bf16x8 xb1 = *(const bf16x8*)&Xt[16+lr][sq];
    const float ev[8] = {e0.x,e0.y,e0.z,e0.w,e1.x,e1.y,e1.z,e1.w};
#pragma unroll
    for (int mt = 0; mt < 4; ++mt) {
      if (ks > ((wave*64 + mt*16 + 15) >> 5)) continue;
      const int l = wave*64 + mt*16 + lr;
      const bf16x8 sb = *(const bf16x8*)(S0b + ((size_t)bc*CH + l)*CH + sq);
      const float el = expf(al[mt] - as0);
      bf16x8 mf;
#pragma unroll
      for (int j = 0; j < 8; ++j) {
        float v = (sq + j <= l) ? bf2f((ushort)sb[j]) * el * ev[j] : 0.f;
        mf[j] = (short)f2bf(v);
      }
      acc[mt][0] = __builtin_amdgcn_mfma_f32_16x16x32_bf16(mf, xb0, acc[mt][0], 0,0,0);
      acc[mt][1] = __builtin_amdgcn_mfma_f32_16x16x32_bf16(mf, xb1, acc[mt][1], 0,0,0);
    }
  }
  const float dph = Dp[h];
#pragma unroll
  for (int mt = 0; mt < 4; ++mt) {
    const int lb = wave*64 + mt*16 + quad*4;
#pragma unroll
    for (int nt = 0; nt < 2; ++nt) {
      const int p = nt*16 + lr;
#pragma unroll
      for (int r = 0; r < 4; ++r) {
        float xv = bf2f(Xt[p][lb+r]);
        Yb[(size_t)(base+lb+r)*DI + h*HD + p] = f2bf(acc[mt][nt][r] + dph*xv);
      }
    }
  }
}

// ---------- gate + RMSNorm, wave-per-row ----------
__global__ __launch_bounds__(256) void k_rms(const ushort* __restrict__ zxb,
                                             const ushort* __restrict__ Yb,
                                             const float* __restrict__ rw,
                                             ushort* __restrict__ yn) {
  const int m = blockIdx.x*4 + (threadIdx.x>>6);
  const int lane = threadIdx.x & 63;
  const int c0 = lane*8;
  bf16x8 zv = *(const bf16x8*)(zxb + (size_t)m*NZX + c0);
  bf16x8 yv = *(const bf16x8*)(Yb  + (size_t)m*DI  + c0);
  float y[8];
  float ss = 0.f;
#pragma unroll
  for (int j = 0; j < 8; ++j) {
    float z = bf2f((ushort)zv[j]);
    y[j] = bf2f((ushort)yv[j]) * z / (1.f + expf(-z));
    ss += y[j]*y[j];
  }
#pragma unroll
  for (int off = 1; off < 64; off <<= 1) ss += __shfl_xor(ss, off);
  const float inv = rsqrtf(ss * (1.f/DI) + EPSV);
  float4 w0 = *(const float4*)&rw[c0];
  float4 w1 = *(const float4*)&rw[c0+4];
  const float wv[8] = {w0.x,w0.y,w0.z,w0.w,w1.x,w1.y,w1.z,w1.w};
  union { ushort u[8]; uint4 q; } pk;
#pragma unroll
  for (int j = 0; j < 8; ++j) pk.u[j] = f2bf(y[j] * inv * wv[j]);
  *(uint4*)(yn + (size_t)m*DI + c0) = pk.q;
}

// ---------- out-proj GEMM (bf16 MFMA, 128x128, double-buffered) + GN partials ----------
__global__ __launch_bounds__(256) void k_gemm_out_mfma(const ushort* __restrict__ ynbf,
                                                       const ushort* __restrict__ wobf,
                                                       ushort* __restrict__ outb,
                                                       float2* __restrict__ gnp) {
  __shared__ ushort As[2][128*40];
  __shared__ ushort Bs[2][128*40];
  const int tid = threadIdx.x;
  const int n0 = blockIdx.x*128, m0 = blockIdx.y*128;
  const int wave = tid>>6, lane = tid&63;
  const int lr = lane&15, quad = lane>>4;
  f32x4 acc[2][8];
#pragma unroll
  for (int mi=0;mi<2;++mi)
#pragma unroll
    for (int ni=0;ni<8;++ni)
#pragma unroll
      for (int r=0;r<4;++r) acc[mi][ni][r] = 0.f;
  const int srow = tid>>1, sc = (tid&1)*16;
  auto LOAD = [&](int buf, int k0) {
    *(uint4*)&As[buf][srow*40 + sc]     = *(const uint4*)(ynbf + (size_t)(m0+srow)*DI + k0 + sc);
    *(uint4*)&As[buf][srow*40 + sc + 8] = *(const uint4*)(ynbf + (size_t)(m0+srow)*DI + k0 + sc + 8);
    *(uint4*)&Bs[buf][srow*40 + sc]     = *(const uint4*)(wobf + (size_t)(n0+srow)*DI + k0 + sc);
    *(uint4*)&Bs[buf][srow*40 + sc + 8] = *(const uint4*)(wobf + (size_t)(n0+srow)*DI + k0 + sc + 8);
  };
  LOAD(0, 0);
#pragma unroll
  for (int i = 0; i < 16; ++i) {
    __syncthreads();
    if (i < 15) LOAD((i+1)&1, (i+1)*32);
    const int cur = i&1;
    bf16x8 af[2], bfr[8];
    af[0] = *(const bf16x8*)&As[cur][(wave*32+lr)*40 + quad*8];
    af[1] = *(const bf16x8*)&As[cur][(wave*32+16+lr)*40 + quad*8];
#pragma unroll
    for (int ni=0;ni<8;++ni) bfr[ni] = *(const bf16x8*)&Bs[cur][(ni*16+lr)*40 + quad*8];
#pragma unroll
    for (int mi=0;mi<2;++mi)
#pragma unroll
      for (int ni=0;ni<8;++ni)
        acc[mi][ni] = __builtin_amdgcn_mfma_f32_16x16x32_bf16(af[mi], bfr[ni], acc[mi][ni], 0, 0, 0);
  }
  const int b = m0 >> 10, l0 = m0 & 1023;
  float sg[4] = {0.f,0.f,0.f,0.f}, sq2[4] = {0.f,0.f,0.f,0.f};
#pragma unroll
  for (int mi=0;mi<2;++mi) {
    int lb = l0 + wave*32 + mi*16 + quad*4;
#pragma unroll
    for (int ni=0;ni<8;++ni) {
      int n = n0 + ni*16 + lr;
      union { ushort u[4]; uint2 q; } pk;
#pragma unroll
      for (int r=0;r<4;++r) pk.u[r] = f2bf(acc[mi][ni][r]);
      *(uint2*)&outb[(size_t)b*DM*L_ + (size_t)n*L_ + lb] = pk.q;
      float ps = acc[mi][ni][0]+acc[mi][ni][1]+acc[mi][ni][2]+acc[mi][ni][3];
      float pq = acc[mi][ni][0]*acc[mi][ni][0]+acc[mi][ni][1]*acc[mi][ni][1]
               + acc[mi][ni][2]*acc[mi][ni][2]+acc[mi][ni][3]*acc[mi][ni][3];
      sg[ni>>1] += ps; sq2[ni>>1] += pq;
    }
  }
#pragma unroll
  for (int g = 0; g < 4; ++g)
#pragma unroll
    for (int off = 32; off > 0; off >>= 1) {
      sg[g]  += __shfl_down(sg[g],  off);
      sq2[g] += __shfl_down(sq2[g], off);
    }
  __shared__ float red[4][8];
  if (lane == 0) {
#pragma unroll
    for (int g = 0; g < 4; ++g) { red[wave][g] = sg[g]; red[wave][4+g] = sq2[g]; }
  }
  __syncthreads();
  if (tid == 0) {
    int g0 = b*8 + (n0>>5);
#pragma unroll
    for (int g = 0; g < 4; ++g) {
      float S = red[0][g]+red[1][g]+red[2][g]+red[3][g];
      float Q = red[0][4+g]+red[1][4+g]+red[2][4+g]+red[3][4+g];
      atomicAdd(&gnp[g0+g].x, S);
      atomicAdd(&gnp[g0+g].y, Q);
    }
  }
}

// ---------- GroupNorm apply + Mish: bf16 in, fp32 out ----------
__global__ __launch_bounds__(256) void k_gn_apply(const float2* __restrict__ gnp,
                                                  const float* __restrict__ gw,
                                                  const float* __restrict__ gb,
                                                  const ushort* __restrict__ ob,
                                                  float* __restrict__ o) {
  const int ch = blockIdx.x & 255, b = blockIdx.x >> 8;
  const int t = threadIdx.x;
  float2 p = gnp[b*8 + (ch>>5)];
  const float mean = p.x * (1.f/(32.f*L_));
  const float var  = p.y * (1.f/(32.f*L_)) - mean*mean;
  const float inv  = rsqrtf(var + EPSV);
  const float w = gw[ch], bb = gb[ch];
  size_t base = (size_t)blockIdx.x * L_;
  ushort4 v = *(const ushort4*)&ob[base + t*4];
  float r[4] = {bf2f(v.x), bf2f(v.y), bf2f(v.z), bf2f(v.w)};
#pragma unroll
  for (int j = 0; j < 4; ++j) {
    float u = (r[j] - mean) * inv * w + bb;
    float m;
    if (u > 15.f) m = u;
    else {
      float e = expf(u);
      float a = 1.f + e;
      float a2 = a*a;
      m = u * (a2 - 1.f) / (a2 + 1.f);
    }
    r[j] = m;
  }
  *(float4*)&o[base + t*4] = make_float4(r[0], r[1], r[2], r[3]);
}

extern "C" void kernel_launch(void* const* d_in, const int* in_sizes, int n_in,
                              void* d_out, int out_size, void* d_ws, size_t ws_size,
                              hipStream_t stream) {
  const float* x       = (const float*)d_in[0];
  const float* W_in    = (const float*)d_in[1];
  const float* conv_w  = (const float*)d_in[2];
  const float* conv_b  = (const float*)d_in[3];
  const float* dt_bias = (const float*)d_in[4];
  const float* A_log   = (const float*)d_in[5];
  const float* Dp      = (const float*)d_in[6];
  const float* rms_w   = (const float*)d_in[7];
  const float* W_out   = (const float*)d_in[8];
  const float* gn_w    = (const float*)d_in[9];
  const float* gn_b    = (const float*)d_in[10];
  float* out = (float*)d_out;
  float* ws  = (float*)d_ws;

  ushort* zxb   = (ushort*)(ws + OFF_ZX);
  ushort* xcb   = (ushort*)(ws + OFF_XC);
  float*  dtp   = ws + OFF_DTP;
  float*  acs   = ws + OFF_ACS;
  ushort* S0b   = (ushort*)(ws + OFF_S0);
  ushort* stb   = (ushort*)(ws + OFF_ST);
  ushort* Ybb   = (ushort*)(ws + OFF_Y);
  ushort* ynbf  = (ushort*)(ws + OFF_YNB);
  ushort* xbf   = (ushort*)(ws + OFF_XBF);
  ushort* wbf   = (ushort*)(ws + OFF_WBF);
  ushort* wobf  = (ushort*)(ws + OFF_WOBF);
  float2* gnp   = (float2*)(ws + OFF_GNP);
  ushort* btg   = (ushort*)(ws + OFF_BT);
  ushort* outb  = (ushort*)(ws + OFF_OUTB);

  k_prep         <<<dim3(512+1296+512+1), 256, 0, stream>>>(x, W_in, W_out, dt_bias,
                                                            xbf, wbf, wobf, gnp, dtp);
  k_gemm_in_mfma <<<dim3(NZX/128, M_/128), 256, 0, stream>>>(xbf, wbf, zxb);
  k_conv         <<<dim3(3, M_/8), 256, 0, stream>>>(zxb, conv_w, conv_b, xcb, btg);
  k_s0st         <<<dim3(26, B_*NC), 256, 0, stream>>>(xcb, btg, dtp, A_log, acs, stb, S0b);
  k_y_mfma       <<<dim3(B_*NC, NH), 256, 0, stream>>>(xcb, dtp, acs, S0b, stb, Dp, Ybb);
  k_rms          <<<dim3(M_/4), 256, 0, stream>>>(zxb, Ybb, rms_w, ynbf);
  k_gemm_out_mfma<<<dim3(DM/128, M_/128), 256, 0, stream>>>(ynbf, wobf, outb, gnp);
  k_gn_apply     <<<dim3(B_*DM), 256, 0, stream>>>(gnp, gn_w, gn_b, outb, out);
}